// Round 1
// baseline (83.284 us; speedup 1.0000x reference)
//
#include <hip/hip_runtime.h>

// out[b] = log( p0*(p1 + p2 - 2*p1*p2) + (1-p0)*p1*p2 ),  pi = exp(lp_i)
// Mathematically identical to the log-space DAG in the reference; all
// intermediates are in [~0.005, 1) so probability-space is fp32-safe.
__device__ __forceinline__ float eval_pc(float lp0, float lp1, float lp2) {
    float p0 = __expf(lp0);
    float p1 = __expf(lp1);
    float p2 = __expf(lp2);
    float p1p2  = p1 * p2;
    float inner = p1 + p2 - 2.0f * p1p2;          // p1(1-p2) + (1-p1)p2
    float tot   = fmaf(p0, inner, (1.0f - p0) * p1p2);
    return __logf(tot);
}

// 4 batch elements per thread: 3 float4 loads (contiguous 48B span), 1 float4 store.
__global__ __launch_bounds__(256) void pc_eval_vec4(const float4* __restrict__ in,
                                                    float4* __restrict__ out,
                                                    int n4) {
    int t = blockIdx.x * blockDim.x + threadIdx.x;
    if (t >= n4) return;
    float4 a = in[3 * t + 0];
    float4 b = in[3 * t + 1];
    float4 c = in[3 * t + 2];
    float4 o;
    o.x = eval_pc(a.x, a.y, a.z);
    o.y = eval_pc(a.w, b.x, b.y);
    o.z = eval_pc(b.z, b.w, c.x);
    o.w = eval_pc(c.y, c.z, c.w);
    out[t] = o;
}

// Scalar tail (not used at B = 2^22, kept for generality).
__global__ void pc_eval_tail(const float* __restrict__ in, float* __restrict__ out,
                             int start, int n) {
    int b = start + blockIdx.x * blockDim.x + threadIdx.x;
    if (b >= n) return;
    out[b] = eval_pc(in[3 * b + 0], in[3 * b + 1], in[3 * b + 2]);
}

extern "C" void kernel_launch(void* const* d_in, const int* in_sizes, int n_in,
                              void* d_out, int out_size, void* d_ws, size_t ws_size,
                              hipStream_t stream) {
    const float* lp = (const float*)d_in[0];
    float* out = (float*)d_out;
    int B  = in_sizes[0] / 3;          // (B, 3) float32
    int n4 = B / 4;                    // B = 4194304, divisible by 4

    const int block = 256;
    int grid = (n4 + block - 1) / block;
    pc_eval_vec4<<<grid, block, 0, stream>>>((const float4*)lp, (float4*)out, n4);

    int done = n4 * 4;
    if (done < B) {
        int rem = B - done;
        pc_eval_tail<<<(rem + block - 1) / block, block, 0, stream>>>(lp, out, done, B);
    }
}